// Round 4
// baseline (3603.812 us; speedup 1.0000x reference)
//
#include <hip/hip_runtime.h>
#include <hip/hip_bf16.h>

typedef unsigned short u16;
typedef unsigned long long u64;
typedef short short8 __attribute__((ext_vector_type(8)));
typedef float floatx4 __attribute__((ext_vector_type(4)));

#define BATCH 64
#define SEQT  256
#define DDIM  1024
#define HDIM  1024
#define GDIM  4096          // 4H
#define MROWS 16384         // B*T
#define NXCD  8

// ---------- helpers ----------
__device__ __forceinline__ u16 f2bf(float f) {
  unsigned u = __builtin_bit_cast(unsigned, f);
  u += 0x7fffu + ((u >> 16) & 1u);
  return (u16)(u >> 16);
}
__device__ __forceinline__ float bf2f(u16 v) {
  unsigned u = ((unsigned)v) << 16;
  return __builtin_bit_cast(float, u);
}
__device__ __forceinline__ float xz2f(float v) { return v; }
__device__ __forceinline__ float xz2f(u16 v) { return bf2f(v); }

template <typename T> __device__ __forceinline__ T f2xz(float v);
template <> __device__ __forceinline__ float f2xz<float>(float v) { return v; }
template <> __device__ __forceinline__ u16 f2xz<u16>(float v) { return f2bf(v); }

__device__ __forceinline__ float sigm(float x) { return 1.0f / (1.0f + __expf(-x)); }
__device__ __forceinline__ float tanh_(float x) {
  float a = __expf(2.0f * fabsf(x));      // inf-safe: a=inf -> r=1
  float r = 1.0f - 2.0f / (a + 1.0f);
  return x >= 0.0f ? r : -r;
}

__device__ __forceinline__ void async16(const void* g, void* l) {
  __builtin_amdgcn_global_load_lds(
      (const __attribute__((address_space(1))) unsigned int*)g,
      (__attribute__((address_space(3))) unsigned int*)l, 16, 0, 0);
}

// agent-scope (LLC-coherent) primitives for the h hand-off
__device__ __forceinline__ void st_agent(unsigned* p, unsigned v) {
  __hip_atomic_store(p, v, __ATOMIC_RELAXED, __HIP_MEMORY_SCOPE_AGENT);
}
__device__ __forceinline__ unsigned ld_agent(const unsigned* p) {
  return __hip_atomic_load(p, __ATOMIC_RELAXED, __HIP_MEMORY_SCOPE_AGENT);
}

// Fence-free grid barrier (per direction, 128 wgs).
__device__ __forceinline__ void grid_barrier(unsigned* arrv, int wd, int l, unsigned epoch) {
  __syncthreads();
  if (threadIdx.x == 0)
    __hip_atomic_store(arrv + wd, epoch, __ATOMIC_RELAXED, __HIP_MEMORY_SCOPE_AGENT);
  if (threadIdx.x < 64) {
    unsigned a, b;
    do {
      __builtin_amdgcn_s_sleep(2);
      a = __hip_atomic_load(arrv + l,      __ATOMIC_RELAXED, __HIP_MEMORY_SCOPE_AGENT);
      b = __hip_atomic_load(arrv + 64 + l, __ATOMIC_RELAXED, __HIP_MEMORY_SCOPE_AGENT);
    } while (!__all(a >= epoch && b >= epoch));
  }
  __syncthreads();
}

// ---------- kernel 1: x fp32 -> bf16 ----------
__global__ __launch_bounds__(256) void k_cvt_x(const float* __restrict__ in,
                                               u16* __restrict__ out) {
  long i = ((long)blockIdx.x * 256 + threadIdx.x) * 4;
  float4 v = *(const float4*)(in + i);
  u16 o0 = f2bf(v.x), o1 = f2bf(v.y), o2 = f2bf(v.z), o3 = f2bf(v.w);
  unsigned lo = (unsigned)o0 | ((unsigned)o1 << 16);
  unsigned hi = (unsigned)o2 | ((unsigned)o3 << 16);
  uint2 p; p.x = lo; p.y = hi;
  *(uint2*)(out + i) = p;
}

// ---------- kernel 2: transpose-convert [1024][4096] fp32 -> [4096][1024] bf16 ----------
__global__ __launch_bounds__(256) void k_tc(const float* __restrict__ S0, const float* __restrict__ S1,
                                            const float* __restrict__ S2, const float* __restrict__ S3,
                                            u16* __restrict__ D0, u16* __restrict__ D1,
                                            u16* __restrict__ D2, u16* __restrict__ D3) {
  const float* src; u16* dst;
  switch (blockIdx.z) {
    case 0: src = S0; dst = D0; break;
    case 1: src = S1; dst = D1; break;
    case 2: src = S2; dst = D2; break;
    default: src = S3; dst = D3; break;
  }
  __shared__ __align__(16) float tl[64][65];
  const int k0 = blockIdx.x * 64, n0 = blockIdx.y * 64;
  const int tid = threadIdx.x, col = tid & 63, rq = tid >> 6;
#pragma unroll
  for (int i = 0; i < 16; i++) {
    int r = i * 4 + rq;
    tl[r][col] = src[(long)(k0 + r) * GDIM + n0 + col];
  }
  __syncthreads();
#pragma unroll
  for (int i = 0; i < 16; i++) {
    int r = i * 4 + rq;
    dst[(long)(n0 + r) * DDIM + k0 + col] = f2bf(tl[col][r]);
  }
}

// ---------- kernel 3: projection GEMM  xz = x_bf16 @ W (+bias) ----------
template <typename XZT>
__global__ __launch_bounds__(256) void k_gemm(const u16* __restrict__ A,
                                              const u16* __restrict__ BtF, const u16* __restrict__ BtB,
                                              const float* __restrict__ biasF, const float* __restrict__ biasB,
                                              XZT* __restrict__ xzF, XZT* __restrict__ xzB) {
  const u16* Bt = blockIdx.z ? BtB : BtF;
  const float* bias = blockIdx.z ? biasB : biasF;
  XZT* xz = blockIdx.z ? xzB : xzF;
  const int m0 = blockIdx.x * 128, n0 = blockIdx.y * 128;
  __shared__ __align__(16) u16 Al[128 * 32];
  __shared__ __align__(16) u16 Bl[128 * 32];
  const int tid = threadIdx.x, w = tid >> 6, l = tid & 63;
  const int wm = w & 1, wn = w >> 1;
  floatx4 acc[4][4];
#pragma unroll
  for (int i = 0; i < 4; i++)
#pragma unroll
    for (int j = 0; j < 4; j++) acc[i][j] = (floatx4)(0.0f);

  const int srow = w * 32 + (l >> 2);
  const char* Ag = (const char*)(A + (long)(m0 + srow) * DDIM) + (l & 3) * 16;
  const char* Bg = (const char*)(Bt + (long)(n0 + srow) * DDIM) + (l & 3) * 16;
  char* Asl = (char*)Al + w * 2048;
  char* Bsl = (char*)Bl + w * 2048;

  for (int kt = 0; kt < 32; kt++) {
    __syncthreads();
    async16(Ag, Asl);
    async16(Ag + 16 * 2048, Asl + 1024);
    async16(Bg, Bsl);
    async16(Bg + 16 * 2048, Bsl + 1024);
    Ag += 64; Bg += 64;
    __syncthreads();
    short8 af[4], bfr[4];
#pragma unroll
    for (int i = 0; i < 4; i++) {
      af[i]  = *(const short8*)(Al + (wm * 64 + i * 16 + (l & 15)) * 32 + (l >> 4) * 8);
      bfr[i] = *(const short8*)(Bl + (wn * 64 + i * 16 + (l & 15)) * 32 + (l >> 4) * 8);
    }
#pragma unroll
    for (int i = 0; i < 4; i++)
#pragma unroll
      for (int j = 0; j < 4; j++)
        acc[i][j] = __builtin_amdgcn_mfma_f32_16x16x32_bf16(af[i], bfr[j], acc[i][j], 0, 0, 0);
  }
  const int c = l & 15, q = l >> 4;
#pragma unroll
  for (int j = 0; j < 4; j++) {
    const int n = n0 + wn * 64 + j * 16 + c;
    const float bv = bias[n];
#pragma unroll
    for (int i = 0; i < 4; i++) {
      const long mb = (long)(m0 + wm * 64 + i * 16 + q * 4);
#pragma unroll
      for (int r = 0; r < 4; r++)
        xz[(mb + r) * GDIM + n] = f2xz<XZT>(acc[i][j][r] + bv);
    }
  }
}

// ---------- kernel 4: persistent LSTM recurrence (both directions) ----------
// Two-level h broadcast, hardened:
//  level 1: per (XCD, dir) group, up to 4 leader wgs copy disjoint 32 KB
//           chunks of h from LLC (sc0 sc1 loads) into a per-group mirror with
//           NORMAL stores (dirty lines in the leader's L2 = intra-XCD
//           coherence point), then atomicAdd an LLC-scope flag.
//  level 2: group members poll the flag, execute buffer_inv sc0 (vL1-only
//           invalidate; L2 is updated in place so it can't be stale), then
//           read the mirror with PLAIN cached loads (32-deep counted vmcnt).
//  canary:  leader 0 of each group writes a magic word (normal store) before
//           barrier 1; each wg reads it after barrier 1 (post-inv plain load).
//           Magic seen  => same L2 as leader => mirror path is coherent.
//           Magic unseen => XCD grouping untrustworthy => per-wg fallback to
//           the R2 LLC-direct read (always correct, just slower).
template <typename XZT>
__global__ __launch_bounds__(256, 1) void k_lstm(const XZT* __restrict__ xzF, const XZT* __restrict__ xzB,
                                                 const u16* __restrict__ UtF, const u16* __restrict__ UtB,
                                                 u16* __restrict__ hbuf, u16* __restrict__ mirror,
                                                 float* __restrict__ out,
                                                 unsigned* __restrict__ bar) {
  const int wg = blockIdx.x;
  const int dir = wg >> 7;
  const int wd = wg & 127;
  const int j0 = wd * 8;
  const int tid = threadIdx.x;
  const int wave = tid >> 6, l = tid & 63;
  const int c = l & 15, q = l >> 4;
  const u16* Ut = dir ? UtB : UtF;
  const XZT* xz = dir ? xzB : xzF;
  unsigned* arrv  = bar + dir * 128;   // words [0,256): arrivals
  unsigned* flags = bar + 256;         // words [256,512): 16 flags, stride 16
  unsigned* cnti  = bar + 512;         // words [512,528): election counters
  unsigned* cany  = bar + 768;         // words 768+g*32: canaries (own 128B lines)
  u16* hb = hbuf + (long)dir * (2 * BATCH * HDIM);

  __shared__ __align__(16) u16 U1[16 * 1032];   // g/o columns, padded rows
  __shared__ float zl[64][33];
  __shared__ unsigned s_xcd, s_old, s_nl, s_use;

  // ---- XCD id + leader election + canary write (once; control memset'd) ----
  if (tid == 0) {
    unsigned xcc;
    asm volatile("s_getreg_b32 %0, hwreg(20, 0, 32)" : "=s"(xcc));  // HW_REG_XCC_ID
    xcc &= 7;
    s_xcd = xcc;
    const unsigned g = xcc * 2 + (unsigned)dir;
    s_old = atomicAdd(&cnti[g], 1u);
    if (s_old == 0)                      // group leader 0: dirty-line canary
      *(volatile unsigned*)&cany[g * 32] = 0xC0FFEE00u | g;
  }

  // stage U tile1 (g,o) into LDS
#pragma unroll
  for (int u8 = 0; u8 < 8; u8++) {
    int unit = u8 * 256 + tid;          // 2048 units of 8 elements
    int r = unit >> 7, kc = unit & 127;
    int zr = (r < 8) ? (2048 + j0 + r) : (3072 + j0 + (r - 8));
    short8 v = *(const short8*)(Ut + (long)zr * DDIM + kc * 8);
    *(short8*)(&U1[r * 1032 + kc * 8]) = v;
  }
  // U tile0 (i,f) into registers: 32 frags = 128 regs (AGPR side of unified file)
  const int zr0 = (c < 8) ? (j0 + c) : (1024 + j0 + (c - 8));
  const int zr1 = zr0 + 2048;
  short8 bU0[32];
#pragma unroll
  for (int kt = 0; kt < 32; kt++)
    bU0[kt] = *(const short8*)(Ut + (long)zr0 * DDIM + kt * 32 + q * 8);

  __syncthreads();
  const unsigned myx = s_xcd;
  const unsigned lidx = s_old;               // <4 -> leader
  const unsigned grp = myx * 2 + (unsigned)dir;
  u16* mirb = mirror + (size_t)grp * (BATCH * HDIM);
  unsigned* flg = flags + grp * 16;

  // elementwise ownership: thread -> (row eb, col pair jj,jj+1)
  const int eb = tid >> 2;
  const int jj = (tid & 3) * 2;
  // zero h parity 0 (agent store: visible at LLC, never dirty in L2)
  st_agent((unsigned*)(hb + eb * HDIM + j0 + jj), 0u);
  float cs0 = 0.0f, cs1 = 0.0f;

  // per-lane byte offset of this lane's h fragment within an h/mirror buffer
  const unsigned hvoff = (unsigned)(((wave * 16 + c) * HDIM + q * 8) * 2);
  // per-lane byte offset for the leader linear copy
  const unsigned cpoff = (unsigned)(wave * 8192 + l * 16);

  // xz prefetch (no h dependency; issued before the barrier each step)
  float xv0[4], xv1[4];
  auto prefetch = [&](int s) {
    const int t = dir ? (SEQT - 1 - s) : s;
#pragma unroll
    for (int r = 0; r < 4; r++) {
      const long row = ((long)(wave * 16 + q * 4 + r) * SEQT + t) * GDIM;
      xv0[r] = xz2f(xz[row + zr0]);
      xv1[r] = xz2f(xz[row + zr1]);
    }
  };
  prefetch(0);

  unsigned nl = 4, use_mir = 0;
  for (int s = 0; s < SEQT; s++) {
    grid_barrier(arrv, wd, l, (unsigned)(s + 1));
    if (s == 0) {                  // all elections + canary stores done
      asm volatile("buffer_inv sc0" ::: "memory");   // vL1-only invalidate
      if (tid == 0) {
        unsigned gsz = ld_agent(&cnti[grp]);
        s_nl = gsz < 4 ? gsz : 4;
        s_use = (*(volatile unsigned*)&cany[grp * 32] == (0xC0FFEE00u | grp)) ? 1u : 0u;
      }
      __syncthreads();
      nl = s_nl; use_mir = s_use;
    }
    const int p = s & 1;
    const int t = dir ? (SEQT - 1 - s) : s;
    const u64 sbase = (u64)(hb + (long)p * (BATCH * HDIM));
    const u64 mbase = (u64)mirb;

    // ---- level 1: leaders copy LLC h -> per-XCD mirror (dirty L2 lines) ----
    if (lidx < 4) {
      for (unsigned ch = lidx; ch < 4; ch += nl) {
        const unsigned cb = ch * 32768u + cpoff;
        short8 cv[8];
#pragma unroll
        for (int i = 0; i < 8; i++)
          asm volatile("global_load_dwordx4 %0, %1, %2 sc0 sc1"
                       : "=v"(cv[i]) : "v"(cb + i * 1024u), "s"(sbase));
#pragma unroll
        for (int i = 0; i < 8; i++) {
          asm volatile("s_waitcnt vmcnt(7)" : "+v"(cv[i]));
          asm volatile("global_store_dwordx4 %0, %1, %2"
                       :: "v"(cb + i * 1024u), "v"(cv[i]), "s"(mbase));
        }
      }
      asm volatile("s_waitcnt vmcnt(0)" ::: "memory");  // stores visible in L2
      __syncthreads();
      if (tid == 0) atomicAdd(flg, 1u);                 // LLC-scope flag bump
    }

    short8 hv[32];
    if (use_mir) {
      // ---- wait for all leaders of this group, invalidate vL1, read L2 ----
      if (tid == 0) {
        const unsigned target = nl * (unsigned)(s + 1);
        while (ld_agent(flg) < target) __builtin_amdgcn_s_sleep(1);
      }
      __syncthreads();
      asm volatile("buffer_inv sc0" ::: "memory");
#pragma unroll
      for (int kt = 0; kt < 32; kt++)
        asm volatile("global_load_dwordx4 %0, %1, %2 offset:%3"
                     : "=v"(hv[kt])
                     : "v"(hvoff), "s"(mbase), "n"(kt * 64));
    } else {
      // ---- fallback: proven R2 LLC-direct read ----
#pragma unroll
      for (int kt = 0; kt < 32; kt++)
        asm volatile("global_load_dwordx4 %0, %1, %2 offset:%3 sc0 sc1"
                     : "=v"(hv[kt])
                     : "v"(hvoff), "s"(sbase), "n"(kt * 64));
    }

    floatx4 a0 = (floatx4)(0.0f), a1 = (floatx4)(0.0f);
#pragma unroll
    for (int kt = 0; kt < 32; kt++) {
      asm volatile("s_waitcnt vmcnt(%1)" : "+v"(hv[kt]) : "n"(31 - kt));
      short8 b1 = *(const short8*)(&U1[c * 1032 + kt * 32 + q * 8]);
      a0 = __builtin_amdgcn_mfma_f32_16x16x32_bf16(hv[kt], bU0[kt], a0, 0, 0, 0);
      a1 = __builtin_amdgcn_mfma_f32_16x16x32_bf16(hv[kt], b1, a1, 0, 0, 0);
    }
#pragma unroll
    for (int r = 0; r < 4; r++) {
      const int m = wave * 16 + q * 4 + r;
      zl[m][c]      = a0[r] + xv0[r];
      zl[m][16 + c] = a1[r] + xv1[r];
    }
    __syncthreads();

    // gates
    float zi0 = zl[eb][jj],      zi1 = zl[eb][jj + 1];
    float zf0 = zl[eb][8 + jj],  zf1 = zl[eb][8 + jj + 1];
    float zg0 = zl[eb][16 + jj], zg1 = zl[eb][16 + jj + 1];
    float zo0 = zl[eb][24 + jj], zo1 = zl[eb][24 + jj + 1];
    float i0 = sigm(zi0), f0 = sigm(zf0), g0 = tanh_(zg0), o0 = sigm(zo0);
    float i1 = sigm(zi1), f1 = sigm(zf1), g1 = tanh_(zg1), o1 = sigm(zo1);
    cs0 = f0 * cs0 + i0 * g0;
    cs1 = f1 * cs1 + i1 * g1;
    float h0v = o0 * tanh_(cs0), h1v = o1 * tanh_(cs1);

    unsigned hpair = (unsigned)f2bf(h0v) | ((unsigned)f2bf(h1v) << 16);
    st_agent((unsigned*)(hb + (long)(1 - p) * (BATCH * HDIM) + eb * HDIM + j0 + jj), hpair);
    float2 op = make_float2(h0v, h1v);
    *(float2*)(out + (long)eb * (SEQT * 2 * HDIM) + (long)t * (2 * HDIM) + dir * HDIM + j0 + jj) = op;

    // issue next step's xz loads now; they drain inside the next barrier
    if (s + 1 < SEQT) prefetch(s + 1);
  }
}

// ---------- host ----------
extern "C" void kernel_launch(void* const* d_in, const int* in_sizes, int n_in,
                              void* d_out, int out_size, void* d_ws, size_t ws_size,
                              hipStream_t stream) {
  const float* x   = (const float*)d_in[0];
  const float* Wf  = (const float*)d_in[1];
  const float* Uf  = (const float*)d_in[2];
  const float* bf_ = (const float*)d_in[3];
  const float* Wb  = (const float*)d_in[4];
  const float* Ub  = (const float*)d_in[5];
  const float* bb  = (const float*)d_in[6];
  float* out = (float*)d_out;
  char* ws = (char*)d_ws;

  const size_t SZ_XBF = (size_t)MROWS * DDIM * 2;        // 32 MB
  const size_t SZ_WT  = (size_t)GDIM * DDIM * 2;         // 8 MB
  const size_t SZ_H   = (size_t)2 * 2 * BATCH * HDIM * 2;
  const size_t SZ_MIR = (size_t)NXCD * 2 * BATCH * HDIM * 2;  // 2 MB

  size_t off = 8192;                       // [0,8192) barrier/flags/cnt/canary
  u16* xbf = (u16*)(ws + off); off += SZ_XBF;
  u16* WtF = (u16*)(ws + off); off += SZ_WT;
  u16* WtB = (u16*)(ws + off); off += SZ_WT;
  u16* UtF = (u16*)(ws + off); off += SZ_WT;
  u16* UtB = (u16*)(ws + off); off += SZ_WT;
  u16* hb  = (u16*)(ws + off); off += SZ_H;
  u16* mir = (u16*)(ws + off); off += SZ_MIR;
  size_t xz_off = (off + 1023) & ~(size_t)1023;

  const size_t XZ_F32 = (size_t)MROWS * GDIM * 4;        // 256 MB each
  const size_t XZ_BF  = (size_t)MROWS * GDIM * 2;        // 128 MB each
  const bool fp32xz = ws_size >= xz_off + 2 * XZ_F32;

  unsigned* bar = (unsigned*)ws;
  hipMemsetAsync(bar, 0, 8192, stream);
  k_cvt_x<<<MROWS * DDIM / 1024, 256, 0, stream>>>(x, xbf);
  k_tc<<<dim3(16, 64, 4), 256, 0, stream>>>(Wf, Uf, Wb, Ub, WtF, UtF, WtB, UtB);

  if (fp32xz) {
    float* xzF = (float*)(ws + xz_off);
    float* xzB = (float*)(ws + xz_off + XZ_F32);
    k_gemm<float><<<dim3(128, 32, 2), 256, 0, stream>>>(xbf, WtF, WtB, bf_, bb, xzF, xzB);
    k_lstm<float><<<256, 256, 0, stream>>>(xzF, xzB, UtF, UtB, hb, mir, out, bar);
  } else {
    u16* xzF = (u16*)(ws + xz_off);
    u16* xzB = (u16*)(ws + xz_off + XZ_BF);
    k_gemm<u16><<<dim3(128, 32, 2), 256, 0, stream>>>(xbf, WtF, WtB, bf_, bb, xzF, xzB);
    k_lstm<u16><<<256, 256, 0, stream>>>(xzF, xzB, UtF, UtB, hb, mir, out, bar);
  }
}

// Round 5
// 3133.384 us; speedup vs baseline: 1.1501x; 1.1501x over previous
//
#include <hip/hip_runtime.h>
#include <hip/hip_bf16.h>

typedef unsigned short u16;
typedef unsigned long long u64;
typedef short short8 __attribute__((ext_vector_type(8)));
typedef float floatx4 __attribute__((ext_vector_type(4)));

#define BATCH 64
#define SEQT  256
#define DDIM  1024
#define HDIM  1024
#define GDIM  4096          // 4H
#define MROWS 16384         // B*T
#define BH    (BATCH * HDIM)   // 65536 elems = 128 KB bf16

// ---------- helpers ----------
__device__ __forceinline__ u16 f2bf(float f) {
  unsigned u = __builtin_bit_cast(unsigned, f);
  u += 0x7fffu + ((u >> 16) & 1u);
  return (u16)(u >> 16);
}
__device__ __forceinline__ float bf2f(u16 v) {
  unsigned u = ((unsigned)v) << 16;
  return __builtin_bit_cast(float, u);
}
__device__ __forceinline__ float xz2f(float v) { return v; }
__device__ __forceinline__ float xz2f(u16 v) { return bf2f(v); }

template <typename T> __device__ __forceinline__ T f2xz(float v);
template <> __device__ __forceinline__ float f2xz<float>(float v) { return v; }
template <> __device__ __forceinline__ u16 f2xz<u16>(float v) { return f2bf(v); }

__device__ __forceinline__ float sigm(float x) { return 1.0f / (1.0f + __expf(-x)); }
__device__ __forceinline__ float tanh_(float x) {
  float a = __expf(2.0f * fabsf(x));      // inf-safe: a=inf -> r=1
  float r = 1.0f - 2.0f / (a + 1.0f);
  return x >= 0.0f ? r : -r;
}

__device__ __forceinline__ void async16(const void* g, void* l) {
  __builtin_amdgcn_global_load_lds(
      (const __attribute__((address_space(1))) unsigned int*)g,
      (__attribute__((address_space(3))) unsigned int*)l, 16, 0, 0);
}

// agent-scope (LLC-coherent) store for the h hand-off (write-around local L2,
// lands at the memory-side LLC = the coherence point)
__device__ __forceinline__ void st_agent(unsigned* p, unsigned v) {
  __hip_atomic_store(p, v, __ATOMIC_RELAXED, __HIP_MEMORY_SCOPE_AGENT);
}

// Fence-free grid barrier (128 wgs total: words [0,64) dir0, [64,128) dir1).
// Ordering: __syncthreads() drains vmcnt (all h agent-stores complete at the
// LLC coherence point) before the leader's arrival store; pollers use
// agent-scope loads (LLC-direct).
__device__ __forceinline__ void grid_barrier(unsigned* bar_, int wdg, int l, unsigned epoch) {
  __syncthreads();
  if (threadIdx.x == 0)
    __hip_atomic_store(bar_ + wdg, epoch, __ATOMIC_RELAXED, __HIP_MEMORY_SCOPE_AGENT);
  if (threadIdx.x < 64) {
    unsigned a, b;
    do {
      __builtin_amdgcn_s_sleep(2);
      a = __hip_atomic_load(bar_ + l,      __ATOMIC_RELAXED, __HIP_MEMORY_SCOPE_AGENT);
      b = __hip_atomic_load(bar_ + 64 + l, __ATOMIC_RELAXED, __HIP_MEMORY_SCOPE_AGENT);
    } while (!__all(a >= epoch && b >= epoch));
  }
  __syncthreads();
}

// ---------- kernel 1: x fp32 -> bf16 ----------
__global__ __launch_bounds__(256) void k_cvt_x(const float* __restrict__ in,
                                               u16* __restrict__ out) {
  long i = ((long)blockIdx.x * 256 + threadIdx.x) * 4;
  float4 v = *(const float4*)(in + i);
  u16 o0 = f2bf(v.x), o1 = f2bf(v.y), o2 = f2bf(v.z), o3 = f2bf(v.w);
  unsigned lo = (unsigned)o0 | ((unsigned)o1 << 16);
  unsigned hi = (unsigned)o2 | ((unsigned)o3 << 16);
  uint2 p; p.x = lo; p.y = hi;
  *(uint2*)(out + i) = p;
}

// ---------- kernel 2: transpose-convert [1024][4096] fp32 -> [4096][1024] bf16 ----------
__global__ __launch_bounds__(256) void k_tc(const float* __restrict__ S0, const float* __restrict__ S1,
                                            const float* __restrict__ S2, const float* __restrict__ S3,
                                            u16* __restrict__ D0, u16* __restrict__ D1,
                                            u16* __restrict__ D2, u16* __restrict__ D3) {
  const float* src; u16* dst;
  switch (blockIdx.z) {
    case 0: src = S0; dst = D0; break;
    case 1: src = S1; dst = D1; break;
    case 2: src = S2; dst = D2; break;
    default: src = S3; dst = D3; break;
  }
  __shared__ __align__(16) float tl[64][65];
  const int k0 = blockIdx.x * 64, n0 = blockIdx.y * 64;
  const int tid = threadIdx.x, col = tid & 63, rq = tid >> 6;
#pragma unroll
  for (int i = 0; i < 16; i++) {
    int r = i * 4 + rq;
    tl[r][col] = src[(long)(k0 + r) * GDIM + n0 + col];
  }
  __syncthreads();
#pragma unroll
  for (int i = 0; i < 16; i++) {
    int r = i * 4 + rq;
    dst[(long)(n0 + r) * DDIM + k0 + col] = f2bf(tl[col][r]);
  }
}

// ---------- kernel 3: projection GEMM  xz = x_bf16 @ W (+bias) ----------
template <typename XZT>
__global__ __launch_bounds__(256) void k_gemm(const u16* __restrict__ A,
                                              const u16* __restrict__ BtF, const u16* __restrict__ BtB,
                                              const float* __restrict__ biasF, const float* __restrict__ biasB,
                                              XZT* __restrict__ xzF, XZT* __restrict__ xzB) {
  const u16* Bt = blockIdx.z ? BtB : BtF;
  const float* bias = blockIdx.z ? biasB : biasF;
  XZT* xz = blockIdx.z ? xzB : xzF;
  const int m0 = blockIdx.x * 128, n0 = blockIdx.y * 128;
  __shared__ __align__(16) u16 Al[128 * 32];
  __shared__ __align__(16) u16 Bl[128 * 32];
  const int tid = threadIdx.x, w = tid >> 6, l = tid & 63;
  const int wm = w & 1, wn = w >> 1;
  floatx4 acc[4][4];
#pragma unroll
  for (int i = 0; i < 4; i++)
#pragma unroll
    for (int j = 0; j < 4; j++) acc[i][j] = (floatx4)(0.0f);

  const int srow = w * 32 + (l >> 2);
  const char* Ag = (const char*)(A + (long)(m0 + srow) * DDIM) + (l & 3) * 16;
  const char* Bg = (const char*)(Bt + (long)(n0 + srow) * DDIM) + (l & 3) * 16;
  char* Asl = (char*)Al + w * 2048;
  char* Bsl = (char*)Bl + w * 2048;

  for (int kt = 0; kt < 32; kt++) {
    __syncthreads();
    async16(Ag, Asl);
    async16(Ag + 16 * 2048, Asl + 1024);
    async16(Bg, Bsl);
    async16(Bg + 16 * 2048, Bsl + 1024);
    Ag += 64; Bg += 64;
    __syncthreads();
    short8 af[4], bfr[4];
#pragma unroll
    for (int i = 0; i < 4; i++) {
      af[i]  = *(const short8*)(Al + (wm * 64 + i * 16 + (l & 15)) * 32 + (l >> 4) * 8);
      bfr[i] = *(const short8*)(Bl + (wn * 64 + i * 16 + (l & 15)) * 32 + (l >> 4) * 8);
    }
#pragma unroll
    for (int i = 0; i < 4; i++)
#pragma unroll
      for (int j = 0; j < 4; j++)
        acc[i][j] = __builtin_amdgcn_mfma_f32_16x16x32_bf16(af[i], bfr[j], acc[i][j], 0, 0, 0);
  }
  const int c = l & 15, q = l >> 4;
#pragma unroll
  for (int j = 0; j < 4; j++) {
    const int n = n0 + wn * 64 + j * 16 + c;
    const float bv = bias[n];
#pragma unroll
    for (int i = 0; i < 4; i++) {
      const long mb = (long)(m0 + wm * 64 + i * 16 + q * 4);
#pragma unroll
      for (int r = 0; r < 4; r++)
        xz[(mb + r) * GDIM + n] = f2xz<XZT>(acc[i][j][r] + bv);
    }
  }
}

// ---------- kernel 4: persistent LSTM recurrence (both directions) ----------
// 128 wgs x 512 threads: wg>>6 = dir, wd = wg&63 = 16-col group (j0 = wd*16).
// Per step:
//  1. grid barrier (drains prev h agent-stores to LLC)
//  2. LINEAR coalesced staging: each wg reads the full 128 KB h with
//     consecutive-lane 16B chunks (1024 B contiguous per wave-instruction =
//     full 128B LLC lines) via sc0 sc1 + counted vmcnt, writes to LDS with
//     the T2 XOR swizzle (byte ^= ((row&7)<<4)). 2 h copies spread hot-line
//     queueing (reader picks wd&1). Total LLC h traffic: 16 MB/step (was 32),
//     and every request is line-coalesced (was 16B stride-2048 scatter).
//  3. MFMA from LDS: wave = (gate g = w&3, row-half rh = w>>2); a-frags via
//     swizzled ds_read_b128 (conflict-free); U-slice (16 cols x K=1024) in
//     128 VGPRs/lane, loaded once per launch.
//  4. zl (64x68 f32) aliases the dead h-LDS (extra __syncthreads fences);
//     total LDS = exactly 131072 B (HK-proven dynamic-LDS size @512 thr).
//  5. gates: thread -> (row eb=tid>>3, col pair jj); h written to BOTH copies
//     of the next parity with agent-scope stores.
template <typename XZT>
__global__ __launch_bounds__(512, 2) void k_lstm(const XZT* __restrict__ xzF, const XZT* __restrict__ xzB,
                                                 const u16* __restrict__ UtF, const u16* __restrict__ UtB,
                                                 u16* __restrict__ hbuf, float* __restrict__ out,
                                                 unsigned* __restrict__ bar) {
  extern __shared__ __align__(16) char lds[];      // 131072 B
  char* hlb = lds;                                  // h tile [64][1024] bf16, swizzled
  float* zl = (float*)lds;                          // aliases h (dead when used)

  const int wg = blockIdx.x;
  const int dir = wg >> 6;
  const int wd = wg & 63;
  const int j0 = wd * 16;
  const int tid = threadIdx.x;
  const int wv = tid >> 6, l = tid & 63;
  const int c = l & 15, q = l >> 4;
  const int g = wv & 3, rh = wv >> 2;               // gate, row-half
  const u16* Ut = dir ? UtB : UtF;
  const XZT* xz = dir ? xzB : xzF;
  u16* hb = hbuf + (size_t)dir * (4 * BH);          // 2 parities x 2 copies

  // U-slice for this wave's gate: 16 cols x K=1024 -> 32 frags = 128 VGPRs
  const int ucol = g * 1024 + j0 + c;
  short8 uf[32];
#pragma unroll
  for (int kt = 0; kt < 32; kt++)
    uf[kt] = *(const short8*)(Ut + (long)ucol * DDIM + kt * 32 + q * 8);

  // elementwise ownership: thread -> (row eb, col pair jj,jj+1) of the 16-col slice
  const int eb = tid >> 3;
  const int jj = (tid & 7) * 2;
  // zero h parity 0, both copies (agent stores: visible at LLC)
  {
    u16* hz = hb + eb * HDIM + j0 + jj;
    st_agent((unsigned*)hz, 0u);
    st_agent((unsigned*)(hz + BH), 0u);
  }
  float cs0 = 0.0f, cs1 = 0.0f;

  // xz prefetch (no h dependency; issued before the barrier each step)
  float xv0[4], xv1[4];
  auto prefetch = [&](int s) {
    const int t = dir ? (SEQT - 1 - s) : s;
#pragma unroll
    for (int r = 0; r < 4; r++) {
      xv0[r] = xz2f(xz[((long)(rh * 32 + q * 4 + r)      * SEQT + t) * GDIM + ucol]);
      xv1[r] = xz2f(xz[((long)(rh * 32 + 16 + q * 4 + r) * SEQT + t) * GDIM + ucol]);
    }
  };
  prefetch(0);

  // ds_read swizzle constants for the MFMA a-frags
  const unsigned swz = ((unsigned)(c & 7)) << 4;
  const unsigned qo = (unsigned)(q * 16);
  const unsigned rbase0 = (unsigned)((rh * 32 + c) * 2048);
  const unsigned rbase1 = rbase0 + 16 * 2048;

  for (int s = 0; s < SEQT; s++) {
    grid_barrier(bar, dir * 64 + wd, l, (unsigned)(s + 1));
    const int p = s & 1;
    const int t = dir ? (SEQT - 1 - s) : s;

    // ---- stage h: linear line-coalesced LLC reads -> swizzled LDS ----
    const u64 sbase = (u64)(hb + (size_t)(2 * p + (wd & 1)) * BH);
#pragma unroll
    for (int rnd = 0; rnd < 2; rnd++) {
      short8 sv[8];
      const unsigned b0 = (unsigned)(rnd * 65536 + tid * 16);
#pragma unroll
      for (int i = 0; i < 8; i++)
        asm volatile("global_load_dwordx4 %0, %1, %2 sc0 sc1"
                     : "=v"(sv[i]) : "v"(b0 + (unsigned)(i * 8192)), "s"(sbase));
#pragma unroll
      for (int i = 0; i < 8; i++) {
        asm volatile("s_waitcnt vmcnt(%1)" : "+v"(sv[i]) : "n"(7 - i));
        const unsigned byte = b0 + (unsigned)(i * 8192);
        const unsigned sw = byte ^ ((byte >> 7) & 0x70u);   // ^((row&7)<<4)
        *(short8*)(hlb + sw) = sv[i];
      }
    }
    __syncthreads();                     // h tile ready in LDS

    // ---- MFMA: z-tile (2 row-blocks x 16 cols of gate g) from LDS h ----
    floatx4 a0 = (floatx4)(0.0f), a1 = (floatx4)(0.0f);
#pragma unroll
    for (int kt = 0; kt < 32; kt++) {
      const unsigned off = (((unsigned)(kt * 64)) | qo) ^ swz;
      short8 af0 = *(const short8*)(hlb + rbase0 + off);
      short8 af1 = *(const short8*)(hlb + rbase1 + off);
      a0 = __builtin_amdgcn_mfma_f32_16x16x32_bf16(af0, uf[kt], a0, 0, 0, 0);
      a1 = __builtin_amdgcn_mfma_f32_16x16x32_bf16(af1, uf[kt], a1, 0, 0, 0);
    }
    __syncthreads();                     // all waves done reading h -> zl may alias

#pragma unroll
    for (int r = 0; r < 4; r++) {
      zl[(rh * 32 + q * 4 + r) * 68 + g * 16 + c]      = a0[r] + xv0[r];
      zl[(rh * 32 + 16 + q * 4 + r) * 68 + g * 16 + c] = a1[r] + xv1[r];
    }
    __syncthreads();                     // zl ready

    // ---- gates ----
    const float* zrow = zl + eb * 68;
    float zi0 = zrow[jj],      zi1 = zrow[jj + 1];
    float zf0 = zrow[16 + jj], zf1 = zrow[16 + jj + 1];
    float zg0 = zrow[32 + jj], zg1 = zrow[32 + jj + 1];
    float zo0 = zrow[48 + jj], zo1 = zrow[48 + jj + 1];
    float i0 = sigm(zi0), f0 = sigm(zf0), g0 = tanh_(zg0), o0 = sigm(zo0);
    float i1 = sigm(zi1), f1 = sigm(zf1), g1 = tanh_(zg1), o1 = sigm(zo1);
    cs0 = f0 * cs0 + i0 * g0;
    cs1 = f1 * cs1 + i1 * g1;
    float h0v = o0 * tanh_(cs0), h1v = o1 * tanh_(cs1);

    unsigned hpair = (unsigned)f2bf(h0v) | ((unsigned)f2bf(h1v) << 16);
    u16* hw = hb + (size_t)(2 * (1 - p)) * BH + eb * HDIM + j0 + jj;
    st_agent((unsigned*)hw, hpair);
    st_agent((unsigned*)(hw + BH), hpair);          // copy 1
    *(float2*)(out + (long)eb * (SEQT * 2 * HDIM) + (long)t * (2 * HDIM) + dir * HDIM + j0 + jj)
        = make_float2(h0v, h1v);

    // issue next step's xz loads now; they drain inside the next barrier
    if (s + 1 < SEQT) prefetch(s + 1);
  }
}

// ---------- host ----------
extern "C" void kernel_launch(void* const* d_in, const int* in_sizes, int n_in,
                              void* d_out, int out_size, void* d_ws, size_t ws_size,
                              hipStream_t stream) {
  const float* x   = (const float*)d_in[0];
  const float* Wf  = (const float*)d_in[1];
  const float* Uf  = (const float*)d_in[2];
  const float* bf_ = (const float*)d_in[3];
  const float* Wb  = (const float*)d_in[4];
  const float* Ub  = (const float*)d_in[5];
  const float* bb  = (const float*)d_in[6];
  float* out = (float*)d_out;
  char* ws = (char*)d_ws;

  const size_t SZ_XBF = (size_t)MROWS * DDIM * 2;        // 32 MB
  const size_t SZ_WT  = (size_t)GDIM * DDIM * 2;         // 8 MB
  const size_t SZ_H   = (size_t)2 * 4 * BH * 2;          // 2 dirs x 2 par x 2 cop = 1 MB

  size_t off = 2048;                       // [0,2048) barrier arrival words
  u16* xbf = (u16*)(ws + off); off += SZ_XBF;
  u16* WtF = (u16*)(ws + off); off += SZ_WT;
  u16* WtB = (u16*)(ws + off); off += SZ_WT;
  u16* UtF = (u16*)(ws + off); off += SZ_WT;
  u16* UtB = (u16*)(ws + off); off += SZ_WT;
  u16* hb  = (u16*)(ws + off); off += SZ_H;
  size_t xz_off = (off + 1023) & ~(size_t)1023;

  const size_t XZ_F32 = (size_t)MROWS * GDIM * 4;        // 256 MB each
  const size_t XZ_BF  = (size_t)MROWS * GDIM * 2;        // 128 MB each
  const bool fp32xz = ws_size >= xz_off + 2 * XZ_F32;

  unsigned* bar = (unsigned*)ws;
  hipMemsetAsync(bar, 0, 2048, stream);
  k_cvt_x<<<MROWS * DDIM / 1024, 256, 0, stream>>>(x, xbf);
  k_tc<<<dim3(16, 64, 4), 256, 0, stream>>>(Wf, Uf, Wb, Ub, WtF, UtF, WtB, UtB);

  if (fp32xz) {
    float* xzF = (float*)(ws + xz_off);
    float* xzB = (float*)(ws + xz_off + XZ_F32);
    k_gemm<float><<<dim3(128, 32, 2), 256, 0, stream>>>(xbf, WtF, WtB, bf_, bb, xzF, xzB);
    hipFuncSetAttribute((const void*)k_lstm<float>,
                        hipFuncAttributeMaxDynamicSharedMemorySize, 131072);
    k_lstm<float><<<128, 512, 131072, stream>>>(xzF, xzB, UtF, UtB, hb, out, bar);
  } else {
    u16* xzF = (u16*)(ws + xz_off);
    u16* xzB = (u16*)(ws + xz_off + XZ_BF);
    k_gemm<u16><<<dim3(128, 32, 2), 256, 0, stream>>>(xbf, WtF, WtB, bf_, bb, xzF, xzB);
    hipFuncSetAttribute((const void*)k_lstm<u16>,
                        hipFuncAttributeMaxDynamicSharedMemorySize, 131072);
    k_lstm<u16><<<128, 512, 131072, stream>>>(xzF, xzB, UtF, UtB, hb, out, bar);
  }
}